// Round 3
// baseline (196.664 us; speedup 1.0000x reference)
//
#include <hip/hip_runtime.h>
#include <math.h>

#define DD 1024
#define HSZ 128
#define NB 4
#define TT 2048

typedef __attribute__((ext_vector_type(8))) short bf16x8;
typedef __attribute__((ext_vector_type(4))) float f32x4;

typedef __attribute__((address_space(3))) unsigned int lds_u32_t;
typedef __attribute__((address_space(1))) unsigned int glb_u32_t;

__device__ inline void gll16(const void* g, void* l) {
    __builtin_amdgcn_global_load_lds((const glb_u32_t*)g, (lds_u32_t*)l, 16, 0, 0);
}

__device__ inline unsigned short f2bf(float f){
    unsigned u = __builtin_bit_cast(unsigned, f);
    u += 0x7fff + ((u >> 16) & 1);
    return (unsigned short)(u >> 16);
}

#define QSCL 0.08838834764831845f

// ---------------- k0: prep = RoPE table + frag-linear weight tiles ----------------
__global__ __launch_bounds__(256) void prep_kernel(
    const float* __restrict__ Wq, const float* __restrict__ Wk,
    const float* __restrict__ Wv, const float* __restrict__ Wo,
    unsigned short* __restrict__ Wbp, unsigned short* __restrict__ Wop,
    float2* __restrict__ tab)
{
    int bid = blockIdx.x, tid = threadIdx.x;
    if (bid < 512) {
        int i = bid * 256 + tid;
        int t = i >> 6, j = i & 63;
        float theta = __powf(10000.f, -(float)j * (1.f / 32.f));
        float ang = (float)t * theta;
        tab[i] = make_float2(__cosf(ang), __sinf(ang));
        return;
    }
    const float* s;
    unsigned short* dst;
    if (bid < 768) {
        int gc = (bid - 512) * 256 + tid;          // < 65536
        int tileid = gc >> 10;
        int ct = tileid >> 4, kk = tileid & 15;
        int ch = gc & 1023;
        int ns = ch >> 7, kc = (ch >> 6) & 1, l6 = ch & 63;
        int wrow = ct * 128 + ns * 16 + (l6 & 15);
        int kcol = kk * 64 + kc * 32 + (l6 >> 4) * 8;
        s = (wrow < 256) ? Wq + (size_t)wrow * DD
          : (wrow < 384) ? Wk + (size_t)(wrow - 256) * DD
                         : Wv + (size_t)(wrow - 384) * DD;
        s += kcol;
        dst = Wbp + (size_t)gc * 8;
    } else {
        int gc = (bid - 768) * 256 + tid;          // < 32768
        int tileid = gc >> 10;
        int ct = tileid >> 2, kk = tileid & 3;
        int ch = gc & 1023;
        int ns = ch >> 7, kc = (ch >> 6) & 1, l6 = ch & 63;
        int orow = ct * 128 + ns * 16 + (l6 & 15);
        int kcol = kk * 64 + kc * 32 + (l6 >> 4) * 8;
        s = Wo + (size_t)orow * 256 + kcol;
        dst = Wop + (size_t)gc * 8;
    }
    float4 a = ((const float4*)s)[0];
    float4 c = ((const float4*)s)[1];
    unsigned short o[8] = {f2bf(a.x),f2bf(a.y),f2bf(a.z),f2bf(a.w),
                           f2bf(c.x),f2bf(c.y),f2bf(c.z),f2bf(c.w)};
    *(uint4*)dst = *(const uint4*)o;
}

// ---------------- k1: QKV GEMM, 64x128 tiles, A direct-frag, B via global_load_lds ----
// q outputs pre-scaled by QSCL (folded out of attention).
__global__ __launch_bounds__(256) void qkv_gemm_kernel(
    const float* __restrict__ x,
    const unsigned short* __restrict__ Wbp,
    const float2* __restrict__ tab,
    unsigned short* __restrict__ qo,
    unsigned short* __restrict__ Kp,
    unsigned short* __restrict__ Vp)
{
    int bid = blockIdx.x;
    int rt = bid & 127, ct = bid >> 7;
    int row0 = rt * 64;
    int b = row0 >> 11, t0 = row0 & (TT - 1);
    int tid = threadIdx.x;
    int wave = tid >> 6, lane = tid & 63;
    int mrow = lane & 15, quad = lane >> 4;

    __shared__ unsigned short Bs[2][8192];

    f32x4 acc[8];
    #pragma unroll
    for (int ns = 0; ns < 8; ++ns)
        #pragma unroll
        for (int r = 0; r < 4; ++r) acc[ns][r] = 0.f;

    const float* xrow = x + (size_t)(row0 + wave * 16 + mrow) * DD;

    {
        const unsigned short* wt = Wbp + (size_t)(ct * 16) * 8192;
        #pragma unroll
        for (int u = 0; u < 4; ++u)
            gll16(wt + (size_t)(u * 256 + tid) * 8, &Bs[0][(u * 256 + (tid & 192)) * 8]);
    }

    for (int kk = 0; kk < 16; ++kk) {
        __syncthreads();
        if (kk < 15) {
            const unsigned short* wt = Wbp + (size_t)(ct * 16 + kk + 1) * 8192;
            #pragma unroll
            for (int u = 0; u < 4; ++u)
                gll16(wt + (size_t)(u * 256 + tid) * 8, &Bs[(kk + 1) & 1][(u * 256 + (tid & 192)) * 8]);
        }
        bf16x8 af[2];
        #pragma unroll
        for (int kc = 0; kc < 2; ++kc) {
            const float* s = xrow + kk * 64 + kc * 32 + quad * 8;
            float4 f0 = ((const float4*)s)[0];
            float4 f1 = ((const float4*)s)[1];
            bf16x8 pk;
            pk[0]=(short)f2bf(f0.x); pk[1]=(short)f2bf(f0.y); pk[2]=(short)f2bf(f0.z); pk[3]=(short)f2bf(f0.w);
            pk[4]=(short)f2bf(f1.x); pk[5]=(short)f2bf(f1.y); pk[6]=(short)f2bf(f1.z); pk[7]=(short)f2bf(f1.w);
            af[kc] = pk;
        }
        const unsigned short* Bcur = Bs[kk & 1];
        #pragma unroll
        for (int kc = 0; kc < 2; ++kc)
            #pragma unroll
            for (int ns = 0; ns < 8; ++ns) {
                bf16x8 bb = *(const bf16x8*)(Bcur + ((ns * 2 + kc) * 64 + lane) * 8);
                acc[ns] = __builtin_amdgcn_mfma_f32_16x16x32_bf16(af[kc], bb, acc[ns], 0, 0, 0);
            }
    }

    __syncthreads();   // all waves done with Bs; safe to reuse for assembly

    if (ct < 2) {
        unsigned short* dst = qo + (size_t)(b * 2 + ct) * TT * HSZ;
        #pragma unroll
        for (int ns = 0; ns < 8; ++ns) {
            int colloc = ns * 16 + mrow;
            int pj = colloc >> 1;
            #pragma unroll
            for (int r = 0; r < 4; ++r) {
                int t = t0 + wave * 16 + quad * 4 + r;
                float v = acc[ns][r];
                float vp = __shfl_xor(v, 1, 64);
                float2 cs = tab[t * 64 + pj];
                float outv = ((mrow & 1) == 0) ? (v * cs.x - vp * cs.y)
                                               : (v * cs.x + vp * cs.y);
                dst[(size_t)t * HSZ + colloc] = f2bf(outv * QSCL);   // pre-scaled q
            }
        }
    } else if (ct == 2) {
        // K with RoPE -> K' frag-linear tile
        unsigned short* A_ = (unsigned short*)Bs;
        #pragma unroll
        for (int ns = 0; ns < 8; ++ns) {
            int colloc = ns * 16 + mrow;
            int pj = colloc >> 1;
            int chunk = (ns >> 1) * 4 + wave;
            int lph = (ns & 1) * 2 + (mrow >> 3);
            #pragma unroll
            for (int r = 0; r < 4; ++r) {
                int t = t0 + wave * 16 + quad * 4 + r;
                float v = acc[ns][r];
                float vp = __shfl_xor(v, 1, 64);
                float2 cs = tab[t * 64 + pj];
                float outv = ((mrow & 1) == 0) ? (v * cs.x - vp * cs.y)
                                               : (v * cs.x + vp * cs.y);
                A_[chunk * 512 + (lph * 16 + quad * 4 + r) * 8 + (mrow & 7)] = f2bf(outv);
            }
        }
        __syncthreads();
        unsigned short* kd = Kp + (size_t)(b * 32 + (t0 >> 6)) * 8192;
        #pragma unroll
        for (int u = 0; u < 4; ++u)
            *(uint4*)(kd + (u * 256 + tid) * 8) = *(const uint4*)(A_ + (u * 256 + tid) * 8);
    } else {
        // V -> V' frag-linear tile
        unsigned short* A_ = (unsigned short*)Bs;
        #pragma unroll
        for (int ns = 0; ns < 8; ++ns) {
            int chunk = ns * 2 + (wave >> 1);
            int lanep = ((wave & 1) * 2 + (quad >> 1)) * 16 + mrow;
            #pragma unroll
            for (int r = 0; r < 4; ++r)
                A_[chunk * 512 + lanep * 8 + (quad & 1) * 4 + r] = f2bf(acc[ns][r]);
        }
        __syncthreads();
        unsigned short* vd = Vp + (size_t)(b * 32 + (t0 >> 6)) * 8192;
        #pragma unroll
        for (int u = 0; u < 4; ++u)
            *(uint4*)(vd + (u * 256 + tid) * 8) = *(const uint4*)(A_ + (u * 256 + tid) * 8);
    }
}

// ---------------- k2: barrier-free flash attention, 16-row q-tiles ----------------
// 1024 blocks = 128 q-tiles x 8 (b,h) -> exactly 4 blocks/CU co-resident.
// 4 waves split the KV loop 4 ways (independent, no per-iter barrier).
// LDS 16.6KB: per-wave P scratch (8KB) aliases the two 8KB pairwise-merge buffers.
// qt chosen so the 4 blocks sharing a CU (bids differing by 256 under round-robin)
// have qt summing to 254 -> uniform per-CU work.
__global__ __launch_bounds__(256, 4) void attn_mfma_kernel(
    const unsigned short* __restrict__ q,
    const unsigned short* __restrict__ Kp,
    const unsigned short* __restrict__ Vp,
    unsigned short* __restrict__ att)
{
    int bid = blockIdx.x;
    int t = bid >> 3;
    int s_ = t >> 5, r_ = t & 31;
    int qt = (s_ == 0) ? r_ : (s_ == 1) ? 63 - r_ : (s_ == 2) ? 64 + r_ : 127 - r_;
    int bh = bid & 7;
    int b = bh >> 1, h = bh & 1;
    int q0 = qt * 16;
    int tid = threadIdx.x;
    int wave = tid >> 6, lane = tid & 63;
    int mrow = lane & 15, quad = lane >> 4;

    __shared__ char raw[16640];
    unsigned short* Psb = (unsigned short*)raw;     // 4 waves x 1024 shorts (aliases bufA/bufB)
    float* bufA = (float*)raw;                      // [0:8K)   16x128 f32
    float* bufB = (float*)(raw + 8192);             // [8K:16K) 16x128 f32
    float* Ms_  = (float*)(raw + 16384);            // 32 floats
    float* Ls_  = Ms_ + 32;                         // 32 floats

    const unsigned short* qbase = q + (((size_t)(b * 2 + h)) * TT + q0 + mrow) * HSZ + quad * 8;
    bf16x8 qf[4];
    #pragma unroll
    for (int c = 0; c < 4; ++c) qf[c] = *(const bf16x8*)(qbase + 32 * c);

    float mrun[4], lrun[4];
    f32x4 O[8];
    #pragma unroll
    for (int r = 0; r < 4; ++r) { mrun[r] = -1e30f; lrun[r] = 0.f; }
    #pragma unroll
    for (int g = 0; g < 8; ++g)
        #pragma unroll
        for (int r = 0; r < 4; ++r) O[g][r] = 0.f;

    const int NT = (qt >> 2) + 1;
    unsigned short* Pw = Psb + wave * 1024;

    for (int j = wave; j < NT; j += 4) {
        const unsigned short* Kt = Kp + (size_t)(b * 32 + j) * 8192;
        const unsigned short* Vt = Vp + (size_t)(b * 32 + j) * 8192;
        int s0 = j * 64;

        f32x4 S[4];
        #pragma unroll
        for (int f = 0; f < 4; ++f)
            #pragma unroll
            for (int r = 0; r < 4; ++r) S[f][r] = 0.f;

        #pragma unroll
        for (int c = 0; c < 4; ++c)
            #pragma unroll
            for (int f = 0; f < 4; ++f) {
                bf16x8 bk = *(const bf16x8*)(Kt + ((c * 4 + f) * 64 + lane) * 8);
                S[f] = __builtin_amdgcn_mfma_f32_16x16x32_bf16(qf[c], bk, S[f], 0, 0, 0);
            }

        if (j == NT - 1) {      // only the diagonal tile needs the causal mask
            #pragma unroll
            for (int f = 0; f < 4; ++f) {
                int sg = s0 + 16 * f + mrow;
                #pragma unroll
                for (int r = 0; r < 4; ++r) {
                    int qg = q0 + quad * 4 + r;
                    S[f][r] = (sg <= qg) ? S[f][r] : -1e30f;
                }
            }
        }

        float al[4];
        #pragma unroll
        for (int r = 0; r < 4; ++r) {
            float v = fmaxf(fmaxf(S[0][r], S[1][r]), fmaxf(S[2][r], S[3][r]));
            v = fmaxf(v, __shfl_xor(v, 1, 64));
            v = fmaxf(v, __shfl_xor(v, 2, 64));
            v = fmaxf(v, __shfl_xor(v, 4, 64));
            v = fmaxf(v, __shfl_xor(v, 8, 64));
            float mn = fmaxf(mrun[r], v);
            al[r] = __expf(mrun[r] - mn);
            mrun[r] = mn;
        }
        #pragma unroll
        for (int f = 0; f < 4; ++f)
            #pragma unroll
            for (int r = 0; r < 4; ++r)
                S[f][r] = __expf(S[f][r] - mrun[r]);
        #pragma unroll
        for (int r = 0; r < 4; ++r) {
            float v = (S[0][r] + S[1][r]) + (S[2][r] + S[3][r]);
            v += __shfl_xor(v, 1, 64);
            v += __shfl_xor(v, 2, 64);
            v += __shfl_xor(v, 4, 64);
            v += __shfl_xor(v, 8, 64);
            lrun[r] = lrun[r] * al[r] + v;
        }
        #pragma unroll
        for (int g = 0; g < 8; ++g) {
            O[g][0] *= al[0]; O[g][1] *= al[1]; O[g][2] *= al[2]; O[g][3] *= al[3];
        }
        // per-wave P transpose via LDS, XOR-swizzled (2 lanes/bank = free)
        #pragma unroll
        for (int f = 0; f < 4; ++f) {
            int p = f >> 1;
            int hi2 = (2 * f + (mrow >> 3)) & 3;
            int jlo = mrow & 7;
            int gx = (quad >> 1) | (hi2 << 1);
            #pragma unroll
            for (int r = 0; r < 4; ++r) {
                int idx = p * 64 + hi2 * 16 + quad * 4 + r;
                Pw[(idx ^ gx) * 8 + jlo] = f2bf(S[f][r]);
            }
        }

        bf16x8 pa[2];
        #pragma unroll
        for (int p = 0; p < 2; ++p) {
            int li = p * 64 + lane;
            int si = li ^ ((li >> 3) & 7);
            pa[p] = *(const bf16x8*)(Pw + si * 8);
        }

        #pragma unroll
        for (int g = 0; g < 8; ++g)
            #pragma unroll
            for (int p = 0; p < 2; ++p) {
                bf16x8 bv = *(const bf16x8*)(Vt + ((g * 2 + p) * 64 + lane) * 8);
                O[g] = __builtin_amdgcn_mfma_f32_16x16x32_bf16(pa[p], bv, O[g], 0, 0, 0);
            }
    }

    // ---- pairwise two-phase merge: (1<-into bufA, 3<-into bufB); (0+A, 2+B); (0 + merged2) ----
    __syncthreads();                       // barrier 1: all P-scratch dead, bufs writable
    if (wave & 1) {                        // waves 1 and 3 publish partials
        float* buf = (wave == 1) ? bufA : bufB;
        int base = (wave == 1) ? 0 : 16;
        #pragma unroll
        for (int g = 0; g < 8; ++g)
            #pragma unroll
            for (int r = 0; r < 4; ++r)
                buf[(quad * 4 + r) * 128 + g * 16 + mrow] = O[g][r];
        if (mrow == 0) {
            #pragma unroll
            for (int r = 0; r < 4; ++r) {
                Ms_[base + quad * 4 + r] = mrun[r];
                Ls_[base + quad * 4 + r] = lrun[r];
            }
        }
    }
    __syncthreads();                       // barrier 2
    if ((wave & 1) == 0) {                 // waves 0 and 2 merge their partner in
        float* buf = (wave == 0) ? bufA : bufB;
        int base = (wave == 0) ? 0 : 16;
        float a0[4], a1[4];
        #pragma unroll
        for (int r = 0; r < 4; ++r) {
            int row = quad * 4 + r;
            float m1 = Ms_[base + row], l1 = Ls_[base + row];
            float mM = fmaxf(mrun[r], m1);
            a0[r] = __expf(mrun[r] - mM);
            a1[r] = __expf(m1 - mM);
            mrun[r] = mM;
            lrun[r] = lrun[r] * a0[r] + l1 * a1[r];
        }
        #pragma unroll
        for (int g = 0; g < 8; ++g)
            #pragma unroll
            for (int r = 0; r < 4; ++r)
                O[g][r] = O[g][r] * a0[r] + buf[(quad * 4 + r) * 128 + g * 16 + mrow] * a1[r];
        if (wave == 2) {                   // republish merged(2,3) into bufB
            #pragma unroll
            for (int g = 0; g < 8; ++g)
                #pragma unroll
                for (int r = 0; r < 4; ++r)
                    bufB[(quad * 4 + r) * 128 + g * 16 + mrow] = O[g][r];
            if (mrow == 0) {
                #pragma unroll
                for (int r = 0; r < 4; ++r) {
                    Ms_[16 + quad * 4 + r] = mrun[r];
                    Ls_[16 + quad * 4 + r] = lrun[r];
                }
            }
        }
    }
    __syncthreads();                       // barrier 3
    if (wave == 0) {                       // final merge + normalized output
        unsigned short* ab = att + (((size_t)b * TT + q0) * 2 + h) * 128;
        float a0[4], a2[4], inv[4];
        #pragma unroll
        for (int r = 0; r < 4; ++r) {
            int row = quad * 4 + r;
            float m2 = Ms_[16 + row], l2 = Ls_[16 + row];
            float mM = fmaxf(mrun[r], m2);
            a0[r] = __expf(mrun[r] - mM);
            a2[r] = __expf(m2 - mM);
            inv[r] = 1.f / (lrun[r] * a0[r] + l2 * a2[r]);
        }
        #pragma unroll
        for (int g = 0; g < 8; ++g)
            #pragma unroll
            for (int r = 0; r < 4; ++r) {
                int row = quad * 4 + r;
                float o = (O[g][r] * a0[r] + bufB[row * 128 + g * 16 + mrow] * a2[r]) * inv[r];
                ab[(size_t)row * 256 + g * 16 + mrow] = f2bf(o);
            }
    }
}

// ---------------- k3: outproj GEMM, A direct-frag from att, B via global_load_lds ----
__global__ __launch_bounds__(256) void outproj_gemm_kernel(
    const unsigned short* __restrict__ attb,
    const unsigned short* __restrict__ Wop,
    float* __restrict__ y)
{
    int bid = blockIdx.x;
    int rt = bid & 127, ct = bid >> 7;
    int row0 = rt * 64;
    int tid = threadIdx.x;
    int wave = tid >> 6, lane = tid & 63;
    int mrow = lane & 15, quad = lane >> 4;

    __shared__ unsigned short Bs[2][8192];

    f32x4 acc[8];
    #pragma unroll
    for (int ns = 0; ns < 8; ++ns)
        #pragma unroll
        for (int r = 0; r < 4; ++r) acc[ns][r] = 0.f;

    const unsigned short* arow = attb + (size_t)(row0 + wave * 16 + mrow) * 256;

    {
        const unsigned short* wt = Wop + (size_t)(ct * 4) * 8192;
        #pragma unroll
        for (int u = 0; u < 4; ++u)
            gll16(wt + (size_t)(u * 256 + tid) * 8, &Bs[0][(u * 256 + (tid & 192)) * 8]);
    }

    for (int kk = 0; kk < 4; ++kk) {
        __syncthreads();
        if (kk < 3) {
            const unsigned short* wt = Wop + (size_t)(ct * 4 + kk + 1) * 8192;
            #pragma unroll
            for (int u = 0; u < 4; ++u)
                gll16(wt + (size_t)(u * 256 + tid) * 8, &Bs[(kk + 1) & 1][(u * 256 + (tid & 192)) * 8]);
        }
        const unsigned short* Bcur = Bs[kk & 1];
        #pragma unroll
        for (int kc = 0; kc < 2; ++kc) {
            bf16x8 af = *(const bf16x8*)(arow + kk * 64 + kc * 32 + quad * 8);
            #pragma unroll
            for (int ns = 0; ns < 8; ++ns) {
                bf16x8 bb = *(const bf16x8*)(Bcur + ((ns * 2 + kc) * 64 + lane) * 8);
                acc[ns] = __builtin_amdgcn_mfma_f32_16x16x32_bf16(af, bb, acc[ns], 0, 0, 0);
            }
        }
    }

    #pragma unroll
    for (int ns = 0; ns < 8; ++ns)
        #pragma unroll
        for (int r = 0; r < 4; ++r) {
            int row = row0 + wave * 16 + quad * 4 + r;
            y[(size_t)row * DD + ct * 128 + ns * 16 + mrow] = acc[ns][r];
        }
}

extern "C" void kernel_launch(void* const* d_in, const int* in_sizes, int n_in,
                              void* d_out, int out_size, void* d_ws, size_t ws_size,
                              hipStream_t stream) {
    const float* x  = (const float*)d_in[0];
    const float* Wq = (const float*)d_in[1];
    const float* Wk = (const float*)d_in[2];
    const float* Wv = (const float*)d_in[3];
    const float* Wo = (const float*)d_in[4];
    float* y = (float*)d_out;

    // ws: att 4MB | qo 4MB | K' 2MB | V' 2MB | Wb' 1MB | Wo' 0.5MB | tab 1MB  (14.5MB)
    char* ws = (char*)d_ws;
    unsigned short* at  = (unsigned short*)(ws);
    unsigned short* qo  = (unsigned short*)(ws + 4u  * 1024 * 1024);
    unsigned short* Kp  = (unsigned short*)(ws + 8u  * 1024 * 1024);
    unsigned short* Vp  = (unsigned short*)(ws + 10u * 1024 * 1024);
    unsigned short* Wbp = (unsigned short*)(ws + 12u * 1024 * 1024);
    unsigned short* Wop = (unsigned short*)(ws + 13u * 1024 * 1024);
    float2*         tb  = (float2*)        (ws + 13824u * 1024);

    prep_kernel<<<896, 256, 0, stream>>>(Wq, Wk, Wv, Wo, Wbp, Wop, tb);
    qkv_gemm_kernel<<<512, 256, 0, stream>>>(x, Wbp, tb, qo, Kp, Vp);
    attn_mfma_kernel<<<1024, 256, 0, stream>>>(qo, Kp, Vp, at);
    outproj_gemm_kernel<<<1024, 256, 0, stream>>>(at, Wop, y);
}